// Round 1
// baseline (779.961 us; speedup 1.0000x reference)
//
#include <hip/hip_runtime.h>

#define BATCH 2048
#define NNEI 64
#define IN_DIM 80
#define EMBED 256
#define NCLS 5
#define NMODES 20
#define NROWS (BATCH * NNEI)   // 131072
#define NEXP (NCLS + 1)        // 6 neighbor experts
#define BPC 256                // blocks per class in nei_gemv

// ---------------- K1: bin (b,n) rows by neighbor label ----------------
__global__ void bin_rows(const int* __restrict__ nei_labels,
                         int* __restrict__ counts, int* __restrict__ lists) {
    int r = blockIdx.x * 256 + threadIdx.x;
    if (r >= NROWS) return;
    int c = nei_labels[r];
    int pos = atomicAdd(&counts[c], 1);
    lists[(size_t)c * NROWS + pos] = r;
}

// ---------------- K2: proj[c][m][o] = mode_b[o] + sum_k modes[c,m,k]*mode_W[256+k][o]
__global__ void mode_proj(const float* __restrict__ modes,
                          const float* __restrict__ mode_W,
                          const float* __restrict__ mode_b,
                          float* __restrict__ proj) {
    int cm = blockIdx.x;            // 0..99  (c*NMODES + m)
    int o = threadIdx.x;            // 0..255
    const float* mv = modes + (size_t)cm * EMBED;
    float acc = mode_b[o];
    #pragma unroll 8
    for (int k = 0; k < EMBED; ++k)
        acc = fmaf(mv[k], mode_W[(size_t)(EMBED + k) * EMBED + o], acc);
    proj[(size_t)cm * EMBED + o] = acc;
}

// ---------------- K3: obs embedding + mode head ----------------
// out0[b][m][o] = (obs_f[b] @ obs_W[c] + obs_b[c]) @ mode_W[0:256] + proj[c][m][o]
#define BPB 4
__global__ __launch_bounds__(256, 2)
void obs_mode(const float* __restrict__ obs, const int* __restrict__ self_labels,
              const float* __restrict__ obs_W, const float* __restrict__ obs_b,
              const float* __restrict__ mode_W, const float* __restrict__ proj,
              float* __restrict__ out0) {
    int b0 = blockIdx.x * BPB;
    int o = threadIdx.x;
    __shared__ float obs_s[BPB][IN_DIM];
    __shared__ float x_s[BPB][EMBED];
    __shared__ int cls_s[BPB];

    for (int t = threadIdx.x; t < BPB * IN_DIM; t += 256) {
        int bb = t / IN_DIM, k = t % IN_DIM;
        obs_s[bb][k] = obs[(size_t)(b0 + bb) * IN_DIM + k];
    }
    if (threadIdx.x < BPB) cls_s[threadIdx.x] = self_labels[b0 + threadIdx.x];
    __syncthreads();

    int c[BPB];
    float xacc[BPB];
    #pragma unroll
    for (int bb = 0; bb < BPB; ++bb) {
        c[bb] = cls_s[bb];
        xacc[bb] = obs_b[c[bb] * EMBED + o];
    }
    #pragma unroll 8
    for (int k = 0; k < IN_DIM; ++k) {
        #pragma unroll
        for (int bb = 0; bb < BPB; ++bb)
            xacc[bb] = fmaf(obs_s[bb][k],
                            obs_W[(size_t)c[bb] * IN_DIM * EMBED + (size_t)k * EMBED + o],
                            xacc[bb]);
    }
    #pragma unroll
    for (int bb = 0; bb < BPB; ++bb) x_s[bb][o] = xacc[bb];
    __syncthreads();

    float tacc[BPB] = {0.f, 0.f, 0.f, 0.f};
    #pragma unroll 8
    for (int k = 0; k < EMBED; ++k) {
        float wv = mode_W[(size_t)k * EMBED + o];
        #pragma unroll
        for (int bb = 0; bb < BPB; ++bb)
            tacc[bb] = fmaf(x_s[bb][k], wv, tacc[bb]);
    }
    #pragma unroll
    for (int bb = 0; bb < BPB; ++bb) {
        const float* pj = proj + (size_t)c[bb] * NMODES * EMBED;
        float* op = out0 + (size_t)(b0 + bb) * NMODES * EMBED;
        for (int m = 0; m < NMODES; ++m)
            op[m * EMBED + o] = tacc[bb] + pj[m * EMBED + o];
    }
}

// ---------------- K4: class-grouped neighbor GEMV ----------------
// For rows of class c: out_n[row][o] = nei_b[c][o] + sum_k r[row][k] * nei_W[c][k][o]
__global__ __launch_bounds__(256, 2)
void nei_gemv(const float* __restrict__ neis,
              const float* __restrict__ nei_W, const float* __restrict__ nei_b,
              const int* __restrict__ counts, const int* __restrict__ lists,
              float* __restrict__ out_n) {
    const int c = blockIdx.x / BPC;
    const int blk = blockIdx.x % BPC;
    const int o = threadIdx.x;
    const int cnt = counts[c];

    // weight-stationary: 80 VGPRs, compile-time indexed only
    float w[IN_DIM];
    #pragma unroll
    for (int k = 0; k < IN_DIM; ++k)
        w[k] = nei_W[(size_t)c * IN_DIM * EMBED + (size_t)k * EMBED + o];
    const float bias = nei_b[c * EMBED + o];

    __shared__ float rbuf[2][IN_DIM];
    const int* mylist = lists + (size_t)c * NROWS;

    int i = blk;
    if (i >= cnt) return;                    // block-uniform

    int row = mylist[i];
    if (o < IN_DIM) {
        float v = neis[(size_t)row * IN_DIM + o];
        rbuf[0][o] = (v >= 0.f) ? 1.f / (v + 1e-4f) : 1.f / (v - 1e-4f);
    }
    __syncthreads();

    int cur = 0;
    while (true) {
        int nxt = i + BPC;
        int nrow = 0;
        bool have_next = (nxt < cnt);
        if (have_next) {
            nrow = mylist[nxt];
            if (o < IN_DIM) {
                float v = neis[(size_t)nrow * IN_DIM + o];
                rbuf[cur ^ 1][o] = (v >= 0.f) ? 1.f / (v + 1e-4f) : 1.f / (v - 1e-4f);
            }
        }
        float acc = bias;
        #pragma unroll
        for (int k4 = 0; k4 < IN_DIM / 4; ++k4) {
            float4 rv = *reinterpret_cast<const float4*>(&rbuf[cur][k4 * 4]);
            acc = fmaf(rv.x, w[k4 * 4 + 0], acc);
            acc = fmaf(rv.y, w[k4 * 4 + 1], acc);
            acc = fmaf(rv.z, w[k4 * 4 + 2], acc);
            acc = fmaf(rv.w, w[k4 * 4 + 3], acc);
        }
        out_n[(size_t)row * EMBED + o] = acc;
        __syncthreads();
        if (!have_next) break;
        i = nxt; row = nrow; cur ^= 1;
    }
}

extern "C" void kernel_launch(void* const* d_in, const int* in_sizes, int n_in,
                              void* d_out, int out_size, void* d_ws, size_t ws_size,
                              hipStream_t stream) {
    const float* obs         = (const float*)d_in[0];
    const float* neis        = (const float*)d_in[1];
    const int*   self_labels = (const int*)d_in[2];
    const int*   nei_labels  = (const int*)d_in[3];
    const float* modes       = (const float*)d_in[4];
    const float* obs_W       = (const float*)d_in[5];
    const float* obs_b       = (const float*)d_in[6];
    const float* nei_W       = (const float*)d_in[7];
    const float* nei_b       = (const float*)d_in[8];
    const float* mode_W      = (const float*)d_in[9];
    const float* mode_b      = (const float*)d_in[10];

    float* out0  = (float*)d_out;
    float* out_n = out0 + (size_t)BATCH * NMODES * EMBED;

    char* ws = (char*)d_ws;
    int* counts = (int*)ws;                               // 24 B
    int* lists  = (int*)(ws + 256);                       // 6*131072*4 = 3145728 B
    float* proj = (float*)(ws + 256 + (size_t)NEXP * NROWS * 4); // 102400 B (offset 256-aligned)

    hipMemsetAsync(counts, 0, NEXP * sizeof(int), stream);

    bin_rows<<<NROWS / 256, 256, 0, stream>>>(nei_labels, counts, lists);
    mode_proj<<<NCLS * NMODES, 256, 0, stream>>>(modes, mode_W, mode_b, proj);
    obs_mode<<<BATCH / BPB, 256, 0, stream>>>(obs, self_labels, obs_W, obs_b,
                                              mode_W, proj, out0);
    nei_gemv<<<NEXP * BPC, 256, 0, stream>>>(neis, nei_W, nei_b, counts, lists, out_n);
}

// Round 2
// 218.955 us; speedup vs baseline: 3.5622x; 3.5622x over previous
//
#include <hip/hip_runtime.h>

#define BATCH 2048
#define NNEI 64
#define IN_DIM 80
#define EMBED 256
#define NCLS 5
#define NMODES 20
#define NROWS (BATCH * NNEI)   // 131072
#define NEXP (NCLS + 1)        // 6 neighbor experts
#define BPC 256                // blocks per class in nei_gemv

// ---------------- K1: bin (b,n) rows by neighbor label ----------------
// Two-level: LDS histogram per block, then 6 global atomics per block.
__global__ void bin_rows(const int* __restrict__ nei_labels,
                         int* __restrict__ counts, int* __restrict__ lists) {
    __shared__ int lcount[NEXP];
    __shared__ int lbase[NEXP];
    int t = threadIdx.x;
    if (t < NEXP) lcount[t] = 0;
    __syncthreads();

    int r = blockIdx.x * 256 + t;
    int c = nei_labels[r];
    int lpos = atomicAdd(&lcount[c], 1);   // LDS atomic — cheap
    __syncthreads();

    if (t < NEXP) lbase[t] = atomicAdd(&counts[t], lcount[t]);  // 6 global atomics/block
    __syncthreads();

    lists[(size_t)c * NROWS + lbase[c] + lpos] = r;
}

// ---------------- K2: proj[c][m][o] = mode_b[o] + sum_k modes[c,m,k]*mode_W[256+k][o]
__global__ void mode_proj(const float* __restrict__ modes,
                          const float* __restrict__ mode_W,
                          const float* __restrict__ mode_b,
                          float* __restrict__ proj) {
    int cm = blockIdx.x;            // 0..99  (c*NMODES + m)
    int o = threadIdx.x;            // 0..255
    const float* mv = modes + (size_t)cm * EMBED;
    float acc = mode_b[o];
    #pragma unroll 8
    for (int k = 0; k < EMBED; ++k)
        acc = fmaf(mv[k], mode_W[(size_t)(EMBED + k) * EMBED + o], acc);
    proj[(size_t)cm * EMBED + o] = acc;
}

// ---------------- K3: obs embedding + mode head ----------------
// out0[b][m][o] = (obs_f[b] @ obs_W[c] + obs_b[c]) @ mode_W[0:256] + proj[c][m][o]
#define BPB 4
__global__ __launch_bounds__(256, 2)
void obs_mode(const float* __restrict__ obs, const int* __restrict__ self_labels,
              const float* __restrict__ obs_W, const float* __restrict__ obs_b,
              const float* __restrict__ mode_W, const float* __restrict__ proj,
              float* __restrict__ out0) {
    int b0 = blockIdx.x * BPB;
    int o = threadIdx.x;
    __shared__ float obs_s[BPB][IN_DIM];
    __shared__ float x_s[BPB][EMBED];
    __shared__ int cls_s[BPB];

    for (int t = threadIdx.x; t < BPB * IN_DIM; t += 256) {
        int bb = t / IN_DIM, k = t % IN_DIM;
        obs_s[bb][k] = obs[(size_t)(b0 + bb) * IN_DIM + k];
    }
    if (threadIdx.x < BPB) cls_s[threadIdx.x] = self_labels[b0 + threadIdx.x];
    __syncthreads();

    int c[BPB];
    float xacc[BPB];
    #pragma unroll
    for (int bb = 0; bb < BPB; ++bb) {
        c[bb] = cls_s[bb];
        xacc[bb] = obs_b[c[bb] * EMBED + o];
    }
    #pragma unroll 8
    for (int k = 0; k < IN_DIM; ++k) {
        #pragma unroll
        for (int bb = 0; bb < BPB; ++bb)
            xacc[bb] = fmaf(obs_s[bb][k],
                            obs_W[(size_t)c[bb] * IN_DIM * EMBED + (size_t)k * EMBED + o],
                            xacc[bb]);
    }
    #pragma unroll
    for (int bb = 0; bb < BPB; ++bb) x_s[bb][o] = xacc[bb];
    __syncthreads();

    float tacc[BPB] = {0.f, 0.f, 0.f, 0.f};
    #pragma unroll 8
    for (int k = 0; k < EMBED; ++k) {
        float wv = mode_W[(size_t)k * EMBED + o];
        #pragma unroll
        for (int bb = 0; bb < BPB; ++bb)
            tacc[bb] = fmaf(x_s[bb][k], wv, tacc[bb]);
    }
    #pragma unroll
    for (int bb = 0; bb < BPB; ++bb) {
        const float* pj = proj + (size_t)c[bb] * NMODES * EMBED;
        float* op = out0 + (size_t)(b0 + bb) * NMODES * EMBED;
        for (int m = 0; m < NMODES; ++m)
            op[m * EMBED + o] = tacc[bb] + pj[m * EMBED + o];
    }
}

// ---------------- K4: class-grouped neighbor GEMV ----------------
// For rows of class c: out_n[row][o] = nei_b[c][o] + sum_k r[row][k] * nei_W[c][k][o]
__global__ __launch_bounds__(256, 2)
void nei_gemv(const float* __restrict__ neis,
              const float* __restrict__ nei_W, const float* __restrict__ nei_b,
              const int* __restrict__ counts, const int* __restrict__ lists,
              float* __restrict__ out_n) {
    const int c = blockIdx.x / BPC;
    const int blk = blockIdx.x % BPC;
    const int o = threadIdx.x;
    const int cnt = counts[c];

    // weight-stationary: 80 VGPRs, compile-time indexed only
    float w[IN_DIM];
    #pragma unroll
    for (int k = 0; k < IN_DIM; ++k)
        w[k] = nei_W[(size_t)c * IN_DIM * EMBED + (size_t)k * EMBED + o];
    const float bias = nei_b[c * EMBED + o];

    __shared__ float rbuf[2][IN_DIM];
    const int* mylist = lists + (size_t)c * NROWS;

    int i = blk;
    if (i >= cnt) return;                    // block-uniform

    int row = mylist[i];
    if (o < IN_DIM) {
        float v = neis[(size_t)row * IN_DIM + o];
        rbuf[0][o] = (v >= 0.f) ? 1.f / (v + 1e-4f) : 1.f / (v - 1e-4f);
    }
    __syncthreads();

    int cur = 0;
    while (true) {
        int nxt = i + BPC;
        int nrow = 0;
        bool have_next = (nxt < cnt);
        if (have_next) {
            nrow = mylist[nxt];
            if (o < IN_DIM) {
                float v = neis[(size_t)nrow * IN_DIM + o];
                rbuf[cur ^ 1][o] = (v >= 0.f) ? 1.f / (v + 1e-4f) : 1.f / (v - 1e-4f);
            }
        }
        float acc = bias;
        #pragma unroll
        for (int k4 = 0; k4 < IN_DIM / 4; ++k4) {
            float4 rv = *reinterpret_cast<const float4*>(&rbuf[cur][k4 * 4]);
            acc = fmaf(rv.x, w[k4 * 4 + 0], acc);
            acc = fmaf(rv.y, w[k4 * 4 + 1], acc);
            acc = fmaf(rv.z, w[k4 * 4 + 2], acc);
            acc = fmaf(rv.w, w[k4 * 4 + 3], acc);
        }
        out_n[(size_t)row * EMBED + o] = acc;
        __syncthreads();
        if (!have_next) break;
        i = nxt; row = nrow; cur ^= 1;
    }
}

extern "C" void kernel_launch(void* const* d_in, const int* in_sizes, int n_in,
                              void* d_out, int out_size, void* d_ws, size_t ws_size,
                              hipStream_t stream) {
    const float* obs         = (const float*)d_in[0];
    const float* neis        = (const float*)d_in[1];
    const int*   self_labels = (const int*)d_in[2];
    const int*   nei_labels  = (const int*)d_in[3];
    const float* modes       = (const float*)d_in[4];
    const float* obs_W       = (const float*)d_in[5];
    const float* obs_b       = (const float*)d_in[6];
    const float* nei_W       = (const float*)d_in[7];
    const float* nei_b       = (const float*)d_in[8];
    const float* mode_W      = (const float*)d_in[9];
    const float* mode_b      = (const float*)d_in[10];

    float* out0  = (float*)d_out;
    float* out_n = out0 + (size_t)BATCH * NMODES * EMBED;

    char* ws = (char*)d_ws;
    int* counts = (int*)ws;                               // 24 B
    int* lists  = (int*)(ws + 256);                       // 6*131072*4 = 3145728 B
    float* proj = (float*)(ws + 256 + (size_t)NEXP * NROWS * 4); // 102400 B

    hipMemsetAsync(counts, 0, NEXP * sizeof(int), stream);

    bin_rows<<<NROWS / 256, 256, 0, stream>>>(nei_labels, counts, lists);
    mode_proj<<<NCLS * NMODES, 256, 0, stream>>>(modes, mode_W, mode_b, proj);
    obs_mode<<<BATCH / BPB, 256, 0, stream>>>(obs, self_labels, obs_W, obs_b,
                                              mode_W, proj, out0);
    nei_gemv<<<NEXP * BPC, 256, 0, stream>>>(neis, nei_W, nei_b, counts, lists, out_n);
}

// Round 3
// 142.786 us; speedup vs baseline: 5.4624x; 1.5334x over previous
//
#include <hip/hip_runtime.h>

#define BATCH 2048
#define NNEI 64
#define IN_DIM 80
#define EMBED 256
#define NCLS 5
#define NMODES 20
#define NROWS (BATCH * NNEI)   // 131072
#define NEXP (NCLS + 1)        // 6 neighbor experts
#define BPC2 256               // blocks per class in nei_gemv_mfma
#define TM 16                  // rows per MFMA tile
#define ASTRIDE 104            // LDS row stride in bf16 elems (bank-conflict-friendly, 16B-aligned)

typedef __attribute__((ext_vector_type(8))) short bf16x8;
typedef __attribute__((ext_vector_type(4))) float f32x4;
typedef __attribute__((ext_vector_type(4))) int i32x4;

__device__ inline unsigned short bf16_rne(float f) {
    unsigned u = __builtin_bit_cast(unsigned, f);
    unsigned r = (u + 0x7fffu + ((u >> 16) & 1u)) >> 16;
    return (unsigned short)r;
}
__device__ inline float bf16_to_f(unsigned short h) {
    unsigned u = ((unsigned)h) << 16;
    return __builtin_bit_cast(float, u);
}

// ---------------- binning: count / scan / place ----------------
__global__ void count_labels(const int* __restrict__ nei_labels, int* __restrict__ counts) {
    __shared__ int lc[NEXP];
    int t = threadIdx.x;
    if (t < NEXP) lc[t] = 0;
    __syncthreads();
    atomicAdd(&lc[nei_labels[blockIdx.x * 256 + t]], 1);
    __syncthreads();
    if (t < NEXP) atomicAdd(&counts[t], lc[t]);
}

__global__ void scan_offsets(const int* __restrict__ counts,
                             int* __restrict__ offsets, int* __restrict__ cursors) {
    int s = 0;
    for (int c = 0; c < NEXP; ++c) { offsets[c] = s; cursors[c] = s; s += counts[c]; }
}

__global__ void place_rows(const int* __restrict__ nei_labels,
                           int* __restrict__ cursors, int* __restrict__ rowids) {
    __shared__ int lc[NEXP], lb[NEXP];
    int t = threadIdx.x;
    if (t < NEXP) lc[t] = 0;
    __syncthreads();
    int r = blockIdx.x * 256 + t;
    int c = nei_labels[r];
    int lpos = atomicAdd(&lc[c], 1);
    __syncthreads();
    if (t < NEXP) lb[t] = atomicAdd(&cursors[t], lc[t]);
    __syncthreads();
    rowids[lb[c] + lpos] = r;
}

// ---------------- W fragment table prep ----------------
// layout: [c][ks(3)][cfg(16)][part(2)][lane(64)][8 bf16]
// value(part=0) = bf16(w), value(part=1) = bf16(w - f32(bf16(w)))
// element j of lane l: k = ks*32 + (l>>4)*8 + j (zero for k>=80), col = cfg*16 + (l&15)
__global__ void wfrag_prep(const float* __restrict__ nei_W, unsigned short* __restrict__ wfrag) {
    int e = blockIdx.x;            // ((c*3+ks)*16+cfg)*2+part, 0..575
    int l = threadIdx.x;           // 0..63
    int part = e & 1;
    int cfg = (e >> 1) & 15;
    int ks = (e >> 5) % 3;
    int c = e / 96;
    int col = cfg * 16 + (l & 15);
    unsigned short v[8] __attribute__((aligned(16)));
    #pragma unroll
    for (int j = 0; j < 8; ++j) {
        int k = ks * 32 + ((l >> 4) * 8) + j;
        float w = (k < IN_DIM) ? nei_W[((size_t)c * IN_DIM + k) * EMBED + col] : 0.f;
        unsigned short h = bf16_rne(w);
        if (part == 0) v[j] = h;
        else v[j] = bf16_rne(w - bf16_to_f(h));
    }
    unsigned short* dst = wfrag + ((size_t)e * 64 + l) * 8;
    *reinterpret_cast<i32x4*>(dst) = *reinterpret_cast<const i32x4*>(v);
}

// ---------------- K2: proj[c][m][o] = mode_b[o] + sum_k modes[c,m,k]*mode_W[256+k][o]
__global__ void mode_proj(const float* __restrict__ modes,
                          const float* __restrict__ mode_W,
                          const float* __restrict__ mode_b,
                          float* __restrict__ proj) {
    int cm = blockIdx.x;            // 0..99
    int o = threadIdx.x;            // 0..255
    const float* mv = modes + (size_t)cm * EMBED;
    float acc = mode_b[o];
    #pragma unroll 8
    for (int k = 0; k < EMBED; ++k)
        acc = fmaf(mv[k], mode_W[(size_t)(EMBED + k) * EMBED + o], acc);
    proj[(size_t)cm * EMBED + o] = acc;
}

// ---------------- K3: obs embedding + mode head ----------------
#define BPB 4
__global__ __launch_bounds__(256, 2)
void obs_mode(const float* __restrict__ obs, const int* __restrict__ self_labels,
              const float* __restrict__ obs_W, const float* __restrict__ obs_b,
              const float* __restrict__ mode_W, const float* __restrict__ proj,
              float* __restrict__ out0) {
    int b0 = blockIdx.x * BPB;
    int o = threadIdx.x;
    __shared__ float obs_s[BPB][IN_DIM];
    __shared__ float x_s[BPB][EMBED];
    __shared__ int cls_s[BPB];

    for (int t = threadIdx.x; t < BPB * IN_DIM; t += 256) {
        int bb = t / IN_DIM, k = t % IN_DIM;
        obs_s[bb][k] = obs[(size_t)(b0 + bb) * IN_DIM + k];
    }
    if (threadIdx.x < BPB) cls_s[threadIdx.x] = self_labels[b0 + threadIdx.x];
    __syncthreads();

    int c[BPB];
    float xacc[BPB];
    #pragma unroll
    for (int bb = 0; bb < BPB; ++bb) {
        c[bb] = cls_s[bb];
        xacc[bb] = obs_b[c[bb] * EMBED + o];
    }
    #pragma unroll 8
    for (int k = 0; k < IN_DIM; ++k) {
        #pragma unroll
        for (int bb = 0; bb < BPB; ++bb)
            xacc[bb] = fmaf(obs_s[bb][k],
                            obs_W[(size_t)c[bb] * IN_DIM * EMBED + (size_t)k * EMBED + o],
                            xacc[bb]);
    }
    #pragma unroll
    for (int bb = 0; bb < BPB; ++bb) x_s[bb][o] = xacc[bb];
    __syncthreads();

    float tacc[BPB] = {0.f, 0.f, 0.f, 0.f};
    #pragma unroll 8
    for (int k = 0; k < EMBED; ++k) {
        float wv = mode_W[(size_t)k * EMBED + o];
        #pragma unroll
        for (int bb = 0; bb < BPB; ++bb)
            tacc[bb] = fmaf(x_s[bb][k], wv, tacc[bb]);
    }
    #pragma unroll
    for (int bb = 0; bb < BPB; ++bb) {
        const float* pj = proj + (size_t)c[bb] * NMODES * EMBED;
        float* op = out0 + (size_t)(b0 + bb) * NMODES * EMBED;
        for (int m = 0; m < NMODES; ++m)
            op[m * EMBED + o] = tacc[bb] + pj[m * EMBED + o];
    }
}

// ---------------- K4: MFMA neighbor GEMM ----------------
// Per class c: out_n[row][o] = nei_b[c][o] + sum_k r[row][k]*nei_W[c][k][o]
// bf16 hi/lo split: r·w ≈ rh·wh + rl·wh + rh·wl  (error ~1e-5 rel)
__global__ __launch_bounds__(256, 2)
void nei_gemv_mfma(const float* __restrict__ neis,
                   const unsigned short* __restrict__ wfrag,
                   const float* __restrict__ nei_b,
                   const int* __restrict__ counts, const int* __restrict__ offsets,
                   const int* __restrict__ rowids,
                   float* __restrict__ out_n) {
    const int c = blockIdx.x / BPC2;
    const int blk = blockIdx.x % BPC2;
    const int cnt = counts[c];
    const int ntiles = (cnt + TM - 1) / TM;
    if (blk >= ntiles) return;

    const int t = threadIdx.x;
    const int wv = t >> 6;     // wave 0..3 -> cols [wv*64, wv*64+64)
    const int l = t & 63;
    const int* mylist = rowids + offsets[c];

    // --- B fragments, register-resident (statically indexed) ---
    bf16x8 wh[3][4], wl[3][4];
    {
        const unsigned short* wb = wfrag + (size_t)c * 96 * 64 * 8;
        #pragma unroll
        for (int ks = 0; ks < 3; ++ks)
            #pragma unroll
            for (int cf = 0; cf < 4; ++cf) {
                size_t base = ((((size_t)ks * 16 + (wv * 4 + cf)) * 2) * 64 + l) * 8;
                wh[ks][cf] = *reinterpret_cast<const bf16x8*>(wb + base);
                wl[ks][cf] = *reinterpret_cast<const bf16x8*>(wb + base + 64 * 8);
            }
    }
    // bias per col fragment
    float bias[4];
    #pragma unroll
    for (int cf = 0; cf < 4; ++cf)
        bias[cf] = nei_b[c * EMBED + (wv * 4 + cf) * 16 + (l & 15)];

    __shared__ __align__(16) unsigned short Ah[TM][ASTRIDE];
    __shared__ __align__(16) unsigned short Al[TM][ASTRIDE];
    __shared__ int rowid_s[TM];

    // zero-pad k = 80..95 once (never overwritten; staging writes only k<80)
    if (t < TM * 16) {
        int r = t >> 4, k = IN_DIM + (t & 15);
        Ah[r][k] = 0; Al[r][k] = 0;
    }

    for (int tile = blk; tile < ntiles; tile += BPC2) {
        __syncthreads();   // prev iteration's MFMA/C-write done

        if (t < TM) {
            int gi = tile * TM + t;
            rowid_s[t] = (gi < cnt) ? mylist[gi] : -1;
        }
        // stage A: 16 rows x 80 floats -> reciprocal -> hi/lo bf16
        #pragma unroll
        for (int jj = 0; jj < 5; ++jj) {
            int f = jj * 256 + t;          // 0..1279
            int row = f / IN_DIM, k = f % IN_DIM;
            int gi = tile * TM + row;
            unsigned short hi = 0, lo = 0;
            if (gi < cnt) {
                int rid = mylist[gi];
                float v = neis[(size_t)rid * IN_DIM + k];
                float r = (v >= 0.f) ? 1.f / (v + 1e-4f) : 1.f / (v - 1e-4f);
                hi = bf16_rne(r);
                lo = bf16_rne(r - bf16_to_f(hi));
            }
            Ah[row][k] = hi;
            Al[row][k] = lo;
        }
        __syncthreads();

        // MFMA phase
        f32x4 acc[4];
        #pragma unroll
        for (int cf = 0; cf < 4; ++cf) acc[cf] = (f32x4){0.f, 0.f, 0.f, 0.f};

        #pragma unroll
        for (int ks = 0; ks < 3; ++ks) {
            const bf16x8 ah = *reinterpret_cast<const bf16x8*>(&Ah[l & 15][ks * 32 + ((l >> 4) << 3)]);
            const bf16x8 al = *reinterpret_cast<const bf16x8*>(&Al[l & 15][ks * 32 + ((l >> 4) << 3)]);
            #pragma unroll
            for (int cf = 0; cf < 4; ++cf) {
                acc[cf] = __builtin_amdgcn_mfma_f32_16x16x32_bf16(ah, wh[ks][cf], acc[cf], 0, 0, 0);
                acc[cf] = __builtin_amdgcn_mfma_f32_16x16x32_bf16(al, wh[ks][cf], acc[cf], 0, 0, 0);
                acc[cf] = __builtin_amdgcn_mfma_f32_16x16x32_bf16(ah, wl[ks][cf], acc[cf], 0, 0, 0);
            }
        }

        // C write: row_local = (l>>4)*4 + i, col = (wv*4+cf)*16 + (l&15)
        int rb = (l >> 4) * 4;
        #pragma unroll
        for (int i = 0; i < 4; ++i) {
            int rid = rowid_s[rb + i];
            if (rid >= 0) {
                float* op = out_n + (size_t)rid * EMBED + (l & 15);
                #pragma unroll
                for (int cf = 0; cf < 4; ++cf)
                    op[(wv * 4 + cf) * 16] = acc[cf][i] + bias[cf];
            }
        }
    }
}

extern "C" void kernel_launch(void* const* d_in, const int* in_sizes, int n_in,
                              void* d_out, int out_size, void* d_ws, size_t ws_size,
                              hipStream_t stream) {
    const float* obs         = (const float*)d_in[0];
    const float* neis        = (const float*)d_in[1];
    const int*   self_labels = (const int*)d_in[2];
    const int*   nei_labels  = (const int*)d_in[3];
    const float* modes       = (const float*)d_in[4];
    const float* obs_W       = (const float*)d_in[5];
    const float* obs_b       = (const float*)d_in[6];
    const float* nei_W       = (const float*)d_in[7];
    const float* nei_b       = (const float*)d_in[8];
    const float* mode_W      = (const float*)d_in[9];
    const float* mode_b      = (const float*)d_in[10];

    float* out0  = (float*)d_out;
    float* out_n = out0 + (size_t)BATCH * NMODES * EMBED;

    char* ws = (char*)d_ws;
    int* counts  = (int*)ws;                     // 24 B
    int* offsets = (int*)(ws + 64);
    int* cursors = (int*)(ws + 128);
    int* rowids  = (int*)(ws + 256);                              // 512 KiB
    float* proj  = (float*)(ws + 256 + (size_t)NROWS * 4);        // 100 KiB
    unsigned short* wfrag = (unsigned short*)(ws + 256 + (size_t)NROWS * 4
                                              + (size_t)NCLS * NMODES * EMBED * 4); // 576 KiB

    hipMemsetAsync(counts, 0, NEXP * sizeof(int), stream);

    count_labels<<<NROWS / 256, 256, 0, stream>>>(nei_labels, counts);
    scan_offsets<<<1, 1, 0, stream>>>(counts, offsets, cursors);
    place_rows<<<NROWS / 256, 256, 0, stream>>>(nei_labels, cursors, rowids);
    wfrag_prep<<<NEXP * 96, 64, 0, stream>>>(nei_W, wfrag);
    mode_proj<<<NCLS * NMODES, 256, 0, stream>>>(modes, mode_W, mode_b, proj);
    obs_mode<<<BATCH / BPB, 256, 0, stream>>>(obs, self_labels, obs_W, obs_b,
                                              mode_W, proj, out0);
    nei_gemv_mfma<<<NEXP * BPC2, 256, 0, stream>>>(neis, wfrag, nei_b,
                                                   counts, offsets, rowids, out_n);
}

// Round 4
// 113.743 us; speedup vs baseline: 6.8572x; 1.2553x over previous
//
#include <hip/hip_runtime.h>

#define BATCH 2048
#define NNEI 64
#define IN_DIM 80
#define EMBED 256
#define NCLS 5
#define NMODES 20
#define NROWS (BATCH * NNEI)   // 131072
#define NEXP (NCLS + 1)        // 6 neighbor experts
#define BPC2 256               // blocks per class in nei_gemv_mfma
#define TM 16                  // rows per MFMA tile

typedef __attribute__((ext_vector_type(8))) short bf16x8;
typedef __attribute__((ext_vector_type(4))) float f32x4;
typedef __attribute__((ext_vector_type(4))) int i32x4;

__device__ inline unsigned short bf16_rne(float f) {
    unsigned u = __builtin_bit_cast(unsigned, f);
    unsigned r = (u + 0x7fffu + ((u >> 16) & 1u)) >> 16;
    return (unsigned short)r;
}
__device__ inline float bf16_to_f(unsigned short h) {
    unsigned u = ((unsigned)h) << 16;
    return __builtin_bit_cast(float, u);
}

// ---------------- binning: count / scan / place ----------------
__global__ void count_labels(const int* __restrict__ nei_labels, int* __restrict__ counts) {
    __shared__ int lc[NEXP];
    int t = threadIdx.x;
    if (t < NEXP) lc[t] = 0;
    __syncthreads();
    atomicAdd(&lc[nei_labels[blockIdx.x * 256 + t]], 1);
    __syncthreads();
    if (t < NEXP) atomicAdd(&counts[t], lc[t]);
}

__global__ void scan_offsets(const int* __restrict__ counts,
                             int* __restrict__ offsets, int* __restrict__ cursors) {
    int s = 0;
    for (int c = 0; c < NEXP; ++c) { offsets[c] = s; cursors[c] = s; s += counts[c]; }
}

__global__ void place_rows(const int* __restrict__ nei_labels,
                           int* __restrict__ cursors, int* __restrict__ rowids) {
    __shared__ int lc[NEXP], lb[NEXP];
    int t = threadIdx.x;
    if (t < NEXP) lc[t] = 0;
    __syncthreads();
    int r = blockIdx.x * 256 + t;
    int c = nei_labels[r];
    int lpos = atomicAdd(&lc[c], 1);
    __syncthreads();
    if (t < NEXP) lb[t] = atomicAdd(&cursors[t], lc[t]);
    __syncthreads();
    rowids[lb[c] + lpos] = r;
}

// ---------------- W fragment table prep ----------------
// layout: [c][ks(3)][cfg(16)][part(2)][lane(64)][8 bf16]
// element j of lane l: k = ks*32 + (l>>4)*8 + j (zero for k>=80), col = cfg*16 + (l&15)
__global__ void wfrag_prep(const float* __restrict__ nei_W, unsigned short* __restrict__ wfrag) {
    int e = blockIdx.x;            // ((c*3+ks)*16+cfg)*2+part, 0..575
    int l = threadIdx.x;           // 0..63
    int part = e & 1;
    int cfg = (e >> 1) & 15;
    int ks = (e >> 5) % 3;
    int c = e / 96;
    int col = cfg * 16 + (l & 15);
    unsigned short v[8] __attribute__((aligned(16)));
    #pragma unroll
    for (int j = 0; j < 8; ++j) {
        int k = ks * 32 + ((l >> 4) * 8) + j;
        float w = (k < IN_DIM) ? nei_W[((size_t)c * IN_DIM + k) * EMBED + col] : 0.f;
        unsigned short h = bf16_rne(w);
        if (part == 0) v[j] = h;
        else v[j] = bf16_rne(w - bf16_to_f(h));
    }
    unsigned short* dst = wfrag + ((size_t)e * 64 + l) * 8;
    *reinterpret_cast<i32x4*>(dst) = *reinterpret_cast<const i32x4*>(v);
}

// ---------------- K2: proj[c][m][o] = mode_b[o] + sum_k modes[c,m,k]*mode_W[256+k][o]
__global__ void mode_proj(const float* __restrict__ modes,
                          const float* __restrict__ mode_W,
                          const float* __restrict__ mode_b,
                          float* __restrict__ proj) {
    int cm = blockIdx.x;            // 0..99
    int o = threadIdx.x;            // 0..255
    const float* mv = modes + (size_t)cm * EMBED;
    float acc = mode_b[o];
    #pragma unroll 8
    for (int k = 0; k < EMBED; ++k)
        acc = fmaf(mv[k], mode_W[(size_t)(EMBED + k) * EMBED + o], acc);
    proj[(size_t)cm * EMBED + o] = acc;
}

// ---------------- K3: obs embedding + mode head ----------------
#define BPB 4
__global__ __launch_bounds__(256, 2)
void obs_mode(const float* __restrict__ obs, const int* __restrict__ self_labels,
              const float* __restrict__ obs_W, const float* __restrict__ obs_b,
              const float* __restrict__ mode_W, const float* __restrict__ proj,
              float* __restrict__ out0) {
    int b0 = blockIdx.x * BPB;
    int o = threadIdx.x;
    __shared__ float obs_s[BPB][IN_DIM];
    __shared__ float x_s[BPB][EMBED];
    __shared__ int cls_s[BPB];

    for (int t = threadIdx.x; t < BPB * IN_DIM; t += 256) {
        int bb = t / IN_DIM, k = t % IN_DIM;
        obs_s[bb][k] = obs[(size_t)(b0 + bb) * IN_DIM + k];
    }
    if (threadIdx.x < BPB) cls_s[threadIdx.x] = self_labels[b0 + threadIdx.x];
    __syncthreads();

    int c[BPB];
    float xacc[BPB];
    #pragma unroll
    for (int bb = 0; bb < BPB; ++bb) {
        c[bb] = cls_s[bb];
        xacc[bb] = obs_b[c[bb] * EMBED + o];
    }
    #pragma unroll 8
    for (int k = 0; k < IN_DIM; ++k) {
        #pragma unroll
        for (int bb = 0; bb < BPB; ++bb)
            xacc[bb] = fmaf(obs_s[bb][k],
                            obs_W[(size_t)c[bb] * IN_DIM * EMBED + (size_t)k * EMBED + o],
                            xacc[bb]);
    }
    #pragma unroll
    for (int bb = 0; bb < BPB; ++bb) x_s[bb][o] = xacc[bb];
    __syncthreads();

    float tacc[BPB] = {0.f, 0.f, 0.f, 0.f};
    #pragma unroll 8
    for (int k = 0; k < EMBED; ++k) {
        float wv = mode_W[(size_t)k * EMBED + o];
        #pragma unroll
        for (int bb = 0; bb < BPB; ++bb)
            tacc[bb] = fmaf(x_s[bb][k], wv, tacc[bb]);
    }
    #pragma unroll
    for (int bb = 0; bb < BPB; ++bb) {
        const float* pj = proj + (size_t)c[bb] * NMODES * EMBED;
        float* op = out0 + (size_t)(b0 + bb) * NMODES * EMBED;
        for (int m = 0; m < NMODES; ++m)
            op[m * EMBED + o] = tacc[bb] + pj[m * EMBED + o];
    }
}

// ---------------- K4: MFMA neighbor GEMM — wave-autonomous, no LDS, no barriers ----
// Per class c: out_n[row][o] = nei_b[c][o] + sum_k r[row][k]*nei_W[c][k][o]
// bf16 hi/lo split: r·w ≈ rh·wh + rl·wh + rh·wl
// Each wave: 16 rows x 64 cols (col-half = wave index in block). A built in registers.
__global__ __launch_bounds__(256)
void nei_gemv_mfma(const float* __restrict__ neis,
                   const unsigned short* __restrict__ wfrag,
                   const float* __restrict__ nei_b,
                   const int* __restrict__ counts, const int* __restrict__ offsets,
                   const int* __restrict__ rowids,
                   float* __restrict__ out_n) {
    const int c = blockIdx.x / BPC2;
    const int blk = blockIdx.x % BPC2;
    const int cnt = counts[c];
    const int ntiles = (cnt + TM - 1) / TM;
    if (blk >= ntiles) return;

    const int ch = threadIdx.x >> 6;   // wave id = col-half 0..3
    const int l = threadIdx.x & 63;
    const int* mylist = rowids + offsets[c];

    // --- B fragments, register-resident (96 VGPR, statically indexed) ---
    bf16x8 wh[3][4], wl[3][4];
    {
        const unsigned short* wb = wfrag + (size_t)c * 96 * 64 * 8;
        #pragma unroll
        for (int ks = 0; ks < 3; ++ks)
            #pragma unroll
            for (int cf = 0; cf < 4; ++cf) {
                size_t base = ((((size_t)ks * 16 + (ch * 4 + cf)) * 2) * 64 + l) * 8;
                wh[ks][cf] = *reinterpret_cast<const bf16x8*>(wb + base);
                wl[ks][cf] = *reinterpret_cast<const bf16x8*>(wb + base + 64 * 8);
            }
    }
    float bias[4];
    #pragma unroll
    for (int cf = 0; cf < 4; ++cf)
        bias[cf] = nei_b[c * EMBED + (ch * 4 + cf) * 16 + (l & 15)];

    const int kc = (l >> 4) * 8;       // lane's k-chunk base within a 32-k slab

    for (int tile = blk; tile < ntiles; tile += BPC2) {
        int gi = tile * TM + (l & 15);
        int rid = mylist[min(gi, cnt - 1)];
        const float* base = neis + (size_t)rid * IN_DIM;

        // load 24 floats (3 ks x 8), aligned float4 pairs; clamp OOB k (B=0 there)
        float f[24];
        #pragma unroll
        for (int ks = 0; ks < 3; ++ks) {
            int k0 = ks * 32 + kc;
            if (k0 + 8 > IN_DIM) k0 = 0;      // lanes whose k>=80: B frag is zero
            float4 x0 = *reinterpret_cast<const float4*>(base + k0);
            float4 x1 = *reinterpret_cast<const float4*>(base + k0 + 4);
            f[ks * 8 + 0] = x0.x; f[ks * 8 + 1] = x0.y; f[ks * 8 + 2] = x0.z; f[ks * 8 + 3] = x0.w;
            f[ks * 8 + 4] = x1.x; f[ks * 8 + 5] = x1.y; f[ks * 8 + 6] = x1.z; f[ks * 8 + 7] = x1.w;
        }

        // reciprocal + hi/lo bf16 pack, in registers
        bf16x8 ah[3], al[3];
        #pragma unroll
        for (int ks = 0; ks < 3; ++ks) {
            #pragma unroll
            for (int j = 0; j < 8; ++j) {
                float v = f[ks * 8 + j];
                float d = (v >= 0.f) ? (v + 1e-4f) : (v - 1e-4f);
                float r = __builtin_amdgcn_rcpf(d);
                unsigned short hi = bf16_rne(r);
                ah[ks][j] = (short)hi;
                al[ks][j] = (short)bf16_rne(r - bf16_to_f(hi));
            }
        }

        f32x4 acc[4];
        #pragma unroll
        for (int cf = 0; cf < 4; ++cf) acc[cf] = (f32x4){0.f, 0.f, 0.f, 0.f};
        #pragma unroll
        for (int ks = 0; ks < 3; ++ks) {
            #pragma unroll
            for (int cf = 0; cf < 4; ++cf) {
                acc[cf] = __builtin_amdgcn_mfma_f32_16x16x32_bf16(ah[ks], wh[ks][cf], acc[cf], 0, 0, 0);
                acc[cf] = __builtin_amdgcn_mfma_f32_16x16x32_bf16(al[ks], wh[ks][cf], acc[cf], 0, 0, 0);
                acc[cf] = __builtin_amdgcn_mfma_f32_16x16x32_bf16(ah[ks], wl[ks][cf], acc[cf], 0, 0, 0);
            }
        }

        // C write: row_local = (l>>4)*4 + i, col = (ch*4+cf)*16 + (l&15)
        int rb = (l >> 4) * 4;
        #pragma unroll
        for (int i = 0; i < 4; ++i) {
            int rid_i = __shfl(rid, rb + i);
            if (tile * TM + rb + i < cnt) {
                float* op = out_n + (size_t)rid_i * EMBED + (l & 15);
                #pragma unroll
                for (int cf = 0; cf < 4; ++cf)
                    op[(ch * 4 + cf) * 16] = acc[cf][i] + bias[cf];
            }
        }
    }
}

extern "C" void kernel_launch(void* const* d_in, const int* in_sizes, int n_in,
                              void* d_out, int out_size, void* d_ws, size_t ws_size,
                              hipStream_t stream) {
    const float* obs         = (const float*)d_in[0];
    const float* neis        = (const float*)d_in[1];
    const int*   self_labels = (const int*)d_in[2];
    const int*   nei_labels  = (const int*)d_in[3];
    const float* modes       = (const float*)d_in[4];
    const float* obs_W       = (const float*)d_in[5];
    const float* obs_b       = (const float*)d_in[6];
    const float* nei_W       = (const float*)d_in[7];
    const float* nei_b       = (const float*)d_in[8];
    const float* mode_W      = (const float*)d_in[9];
    const float* mode_b      = (const float*)d_in[10];

    float* out0  = (float*)d_out;
    float* out_n = out0 + (size_t)BATCH * NMODES * EMBED;

    char* ws = (char*)d_ws;
    int* counts  = (int*)ws;                     // 24 B
    int* offsets = (int*)(ws + 64);
    int* cursors = (int*)(ws + 128);
    int* rowids  = (int*)(ws + 256);                              // 512 KiB
    float* proj  = (float*)(ws + 256 + (size_t)NROWS * 4);        // 100 KiB
    unsigned short* wfrag = (unsigned short*)(ws + 256 + (size_t)NROWS * 4
                                              + (size_t)NCLS * NMODES * EMBED * 4); // 576 KiB

    hipMemsetAsync(counts, 0, NEXP * sizeof(int), stream);

    count_labels<<<NROWS / 256, 256, 0, stream>>>(nei_labels, counts);
    scan_offsets<<<1, 1, 0, stream>>>(counts, offsets, cursors);
    place_rows<<<NROWS / 256, 256, 0, stream>>>(nei_labels, cursors, rowids);
    wfrag_prep<<<NEXP * 96, 64, 0, stream>>>(nei_W, wfrag);
    mode_proj<<<NCLS * NMODES, 256, 0, stream>>>(modes, mode_W, mode_b, proj);
    obs_mode<<<BATCH / BPB, 256, 0, stream>>>(obs, self_labels, obs_W, obs_b,
                                              mode_W, proj, out0);
    nei_gemv_mfma<<<NEXP * BPC2, 256, 0, stream>>>(neis, wfrag, nei_b,
                                                   counts, offsets, rowids, out_n);
}

// Round 5
// 111.001 us; speedup vs baseline: 7.0266x; 1.0247x over previous
//
#include <hip/hip_runtime.h>

#define BATCH 2048
#define NNEI 64
#define IN_DIM 80
#define EMBED 256
#define NCLS 5
#define NMODES 20
#define NROWS (BATCH * NNEI)   // 131072
#define NEXP (NCLS + 1)        // 6 neighbor experts
#define TM 16                  // rows per MFMA tile
#define GRID2 512              // persistent blocks for nei_gemv (2/CU)

typedef __attribute__((ext_vector_type(8))) short bf16x8;
typedef __attribute__((ext_vector_type(4))) float f32x4;
typedef __attribute__((ext_vector_type(4))) int i32x4;

__device__ inline unsigned short bf16_rne(float f) {
    unsigned u = __builtin_bit_cast(unsigned, f);
    unsigned r = (u + 0x7fffu + ((u >> 16) & 1u)) >> 16;
    return (unsigned short)r;
}
__device__ inline float bf16_to_f(unsigned short h) {
    unsigned u = ((unsigned)h) << 16;
    return __builtin_bit_cast(float, u);
}

// ---------------- K1: bin rows by label (single pass; per-class region c*NROWS) ----
__global__ void bin_rows(const int* __restrict__ nei_labels,
                         int* __restrict__ counts, int* __restrict__ lists) {
    __shared__ int lc[NEXP], lb[NEXP];
    int t = threadIdx.x;
    if (t < NEXP) lc[t] = 0;
    __syncthreads();
    int r = blockIdx.x * 256 + t;
    int c = nei_labels[r];
    int lpos = atomicAdd(&lc[c], 1);
    __syncthreads();
    if (t < NEXP) lb[t] = atomicAdd(&counts[t], lc[t]);
    __syncthreads();
    lists[(size_t)c * NROWS + lb[c] + lpos] = r;
}

// ---------------- W fragment table prep ----------------
// layout: [c][ks(3)][cfg(16)][part(2)][lane(64)][8 bf16]
// element j of lane l: k = ks*32 + (l>>4)*8 + j (zero for k>=80), col = cfg*16 + (l&15)
__global__ void wfrag_prep(const float* __restrict__ nei_W, unsigned short* __restrict__ wfrag) {
    int e = blockIdx.x;            // ((c*3+ks)*16+cfg)*2+part, 0..575
    int l = threadIdx.x;           // 0..63
    int part = e & 1;
    int cfg = (e >> 1) & 15;
    int ks = (e >> 5) % 3;
    int c = e / 96;
    int col = cfg * 16 + (l & 15);
    unsigned short v[8] __attribute__((aligned(16)));
    #pragma unroll
    for (int j = 0; j < 8; ++j) {
        int k = ks * 32 + ((l >> 4) * 8) + j;
        float w = (k < IN_DIM) ? nei_W[((size_t)c * IN_DIM + k) * EMBED + col] : 0.f;
        unsigned short h = bf16_rne(w);
        if (part == 0) v[j] = h;
        else v[j] = bf16_rne(w - bf16_to_f(h));
    }
    unsigned short* dst = wfrag + ((size_t)e * 64 + l) * 8;
    *reinterpret_cast<i32x4*>(dst) = *reinterpret_cast<const i32x4*>(v);
}

// ---------------- K2: proj[c][m][o] = mode_b[o] + sum_k modes[c,m,k]*mode_W[256+k][o]
__global__ void mode_proj(const float* __restrict__ modes,
                          const float* __restrict__ mode_W,
                          const float* __restrict__ mode_b,
                          float* __restrict__ proj) {
    int cm = blockIdx.x;            // 0..99
    int o = threadIdx.x;            // 0..255
    const float* mv = modes + (size_t)cm * EMBED;
    float acc = mode_b[o];
    #pragma unroll 8
    for (int k = 0; k < EMBED; ++k)
        acc = fmaf(mv[k], mode_W[(size_t)(EMBED + k) * EMBED + o], acc);
    proj[(size_t)cm * EMBED + o] = acc;
}

// ---------------- K3: obs embedding + mode head ----------------
#define BPB 8
__global__ __launch_bounds__(256, 2)
void obs_mode(const float* __restrict__ obs, const int* __restrict__ self_labels,
              const float* __restrict__ obs_W, const float* __restrict__ obs_b,
              const float* __restrict__ mode_W, const float* __restrict__ proj,
              float* __restrict__ out0) {
    int b0 = blockIdx.x * BPB;
    int o = threadIdx.x;
    __shared__ float obs_s[BPB][IN_DIM];
    __shared__ float x_s[BPB][EMBED];
    __shared__ int cls_s[BPB];

    for (int t = threadIdx.x; t < BPB * IN_DIM; t += 256) {
        int bb = t / IN_DIM, k = t % IN_DIM;
        obs_s[bb][k] = obs[(size_t)(b0 + bb) * IN_DIM + k];
    }
    if (threadIdx.x < BPB) cls_s[threadIdx.x] = self_labels[b0 + threadIdx.x];
    __syncthreads();

    int c[BPB];
    float xacc[BPB];
    #pragma unroll
    for (int bb = 0; bb < BPB; ++bb) {
        c[bb] = cls_s[bb];
        xacc[bb] = obs_b[c[bb] * EMBED + o];
    }
    #pragma unroll 4
    for (int k = 0; k < IN_DIM; ++k) {
        #pragma unroll
        for (int bb = 0; bb < BPB; ++bb)
            xacc[bb] = fmaf(obs_s[bb][k],
                            obs_W[(size_t)c[bb] * IN_DIM * EMBED + (size_t)k * EMBED + o],
                            xacc[bb]);
    }
    #pragma unroll
    for (int bb = 0; bb < BPB; ++bb) x_s[bb][o] = xacc[bb];
    __syncthreads();

    float tacc[BPB];
    #pragma unroll
    for (int bb = 0; bb < BPB; ++bb) tacc[bb] = 0.f;
    #pragma unroll 4
    for (int k = 0; k < EMBED; ++k) {
        float wv = mode_W[(size_t)k * EMBED + o];
        #pragma unroll
        for (int bb = 0; bb < BPB; ++bb)
            tacc[bb] = fmaf(x_s[bb][k], wv, tacc[bb]);
    }
    #pragma unroll
    for (int bb = 0; bb < BPB; ++bb) {
        const float* pj = proj + (size_t)c[bb] * NMODES * EMBED;
        float* op = out0 + (size_t)(b0 + bb) * NMODES * EMBED;
        for (int m = 0; m < NMODES; ++m)
            op[m * EMBED + o] = tacc[bb] + pj[m * EMBED + o];
    }
}

// ---------------- K4: MFMA neighbor GEMM — persistent, prefetched, no LDS/barriers ----
// Per class c: out_n[row][o] = nei_b[c][o] + sum_k r[row][k]*nei_W[c][k][o]
// bf16 hi/lo split: r·w ≈ rh·wh + rl·wh + rh·wl
__global__ __launch_bounds__(256, 2)
void nei_gemv_mfma(const float* __restrict__ neis,
                   const unsigned short* __restrict__ wfrag,
                   const float* __restrict__ nei_b,
                   const int* __restrict__ counts,
                   const int* __restrict__ lists,
                   float* __restrict__ out_n) {
    const int b = blockIdx.x;
    const int c = (b * NEXP) / GRID2;                    // contiguous class ranges
    const int cstart = (c * GRID2 + NEXP - 1) / NEXP;
    const int cend = ((c + 1) * GRID2 + NEXP - 1) / NEXP;
    const int blk = b - cstart;
    const int nblk = cend - cstart;
    const int cnt = counts[c];
    const int ntiles = (cnt + TM - 1) / TM;
    if (blk >= ntiles || cnt == 0) return;

    const int ch = threadIdx.x >> 6;   // wave id = col-quarter 0..3
    const int l = threadIdx.x & 63;
    const int* mylist = lists + (size_t)c * NROWS;
    const int kc = (l >> 4) * 8;       // lane's k-chunk base within a 32-k slab

    // --- B fragments, register-resident (96 VGPR, statically indexed) ---
    bf16x8 wh[3][4], wl[3][4];
    {
        const unsigned short* wb = wfrag + (size_t)c * 96 * 64 * 8;
        #pragma unroll
        for (int ks = 0; ks < 3; ++ks)
            #pragma unroll
            for (int cf = 0; cf < 4; ++cf) {
                size_t base = ((((size_t)ks * 16 + (ch * 4 + cf)) * 2) * 64 + l) * 8;
                wh[ks][cf] = *reinterpret_cast<const bf16x8*>(wb + base);
                wl[ks][cf] = *reinterpret_cast<const bf16x8*>(wb + base + 64 * 8);
            }
    }
    float bias[4];
    #pragma unroll
    for (int cf = 0; cf < 4; ++cf)
        bias[cf] = nei_b[c * EMBED + (ch * 4 + cf) * 16 + (l & 15)];

#define LOADT(F, R, T) {                                                      \
    int gi_ = (T) * TM + (l & 15);                                            \
    R = mylist[min(gi_, cnt - 1)];                                            \
    const float* bp_ = neis + (size_t)(unsigned)R * IN_DIM;                   \
    _Pragma("unroll")                                                         \
    for (int ks_ = 0; ks_ < 3; ++ks_) {                                       \
        int k0_ = ks_ * 32 + kc;                                              \
        if (k0_ + 8 > IN_DIM) k0_ = 0; /* B frag is zero for k>=80 */         \
        *reinterpret_cast<float4*>(&F[ks_ * 8])     = *reinterpret_cast<const float4*>(bp_ + k0_);     \
        *reinterpret_cast<float4*>(&F[ks_ * 8 + 4]) = *reinterpret_cast<const float4*>(bp_ + k0_ + 4); \
    } }

#define COMPT(F, R, T) {                                                      \
    bf16x8 ah_[3], al_[3];                                                    \
    _Pragma("unroll")                                                         \
    for (int ks_ = 0; ks_ < 3; ++ks_) {                                       \
        _Pragma("unroll")                                                     \
        for (int j_ = 0; j_ < 8; ++j_) {                                      \
            float v_ = F[ks_ * 8 + j_];                                       \
            float d_ = (v_ >= 0.f) ? (v_ + 1e-4f) : (v_ - 1e-4f);             \
            float r_ = __builtin_amdgcn_rcpf(d_);                             \
            unsigned short hi_ = bf16_rne(r_);                                \
            ah_[ks_][j_] = (short)hi_;                                        \
            al_[ks_][j_] = (short)bf16_rne(r_ - bf16_to_f(hi_));              \
        }                                                                     \
    }                                                                         \
    f32x4 acc_[4];                                                            \
    _Pragma("unroll")                                                         \
    for (int cf_ = 0; cf_ < 4; ++cf_) acc_[cf_] = (f32x4){0.f, 0.f, 0.f, 0.f};\
    _Pragma("unroll")                                                         \
    for (int ks_ = 0; ks_ < 3; ++ks_) {                                       \
        _Pragma("unroll")                                                     \
        for (int cf_ = 0; cf_ < 4; ++cf_) {                                   \
            acc_[cf_] = __builtin_amdgcn_mfma_f32_16x16x32_bf16(ah_[ks_], wh[ks_][cf_], acc_[cf_], 0, 0, 0); \
            acc_[cf_] = __builtin_amdgcn_mfma_f32_16x16x32_bf16(al_[ks_], wh[ks_][cf_], acc_[cf_], 0, 0, 0); \
            acc_[cf_] = __builtin_amdgcn_mfma_f32_16x16x32_bf16(ah_[ks_], wl[ks_][cf_], acc_[cf_], 0, 0, 0); \
        }                                                                     \
    }                                                                         \
    int rb_ = (l >> 4) * 4;                                                   \
    _Pragma("unroll")                                                         \
    for (int i_ = 0; i_ < 4; ++i_) {                                          \
        int rid_ = __shfl(R, rb_ + i_);                                       \
        if ((T) * TM + rb_ + i_ < cnt) {                                      \
            float* op_ = out_n + (size_t)(unsigned)rid_ * EMBED + (l & 15);   \
            _Pragma("unroll")                                                 \
            for (int cf_ = 0; cf_ < 4; ++cf_)                                 \
                op_[(ch * 4 + cf_) * 16] = acc_[cf_][i_] + bias[cf_];         \
        }                                                                     \
    } }

    float fA[24], fB[24];
    int ridA, ridB;
    int tile = blk;
    LOADT(fA, ridA, tile)
    while (true) {
        int nt = tile + nblk;
        bool hn = nt < ntiles;
        if (hn) LOADT(fB, ridB, nt)       // prefetch overlaps compute below
        COMPT(fA, ridA, tile)
        if (!hn) break;
        tile = nt;
        nt = tile + nblk;
        hn = nt < ntiles;
        if (hn) LOADT(fA, ridA, nt)
        COMPT(fB, ridB, tile)
        if (!hn) break;
        tile = nt;
    }
#undef LOADT
#undef COMPT
}

extern "C" void kernel_launch(void* const* d_in, const int* in_sizes, int n_in,
                              void* d_out, int out_size, void* d_ws, size_t ws_size,
                              hipStream_t stream) {
    const float* obs         = (const float*)d_in[0];
    const float* neis        = (const float*)d_in[1];
    const int*   self_labels = (const int*)d_in[2];
    const int*   nei_labels  = (const int*)d_in[3];
    const float* modes       = (const float*)d_in[4];
    const float* obs_W       = (const float*)d_in[5];
    const float* obs_b       = (const float*)d_in[6];
    const float* nei_W       = (const float*)d_in[7];
    const float* nei_b       = (const float*)d_in[8];
    const float* mode_W      = (const float*)d_in[9];
    const float* mode_b      = (const float*)d_in[10];

    float* out0  = (float*)d_out;
    float* out_n = out0 + (size_t)BATCH * NMODES * EMBED;

    char* ws = (char*)d_ws;
    int* counts = (int*)ws;                                        // 24 B
    int* lists  = (int*)(ws + 256);                                // 6*131072*4 = 3 MiB
    float* proj = (float*)(ws + 256 + (size_t)NEXP * NROWS * 4);   // 100 KiB
    unsigned short* wfrag = (unsigned short*)(ws + 256 + (size_t)NEXP * NROWS * 4
                                              + (size_t)NCLS * NMODES * EMBED * 4); // 576 KiB

    hipMemsetAsync(counts, 0, NEXP * sizeof(int), stream);

    bin_rows<<<NROWS / 256, 256, 0, stream>>>(nei_labels, counts, lists);
    wfrag_prep<<<NEXP * 96, 64, 0, stream>>>(nei_W, wfrag);
    mode_proj<<<NCLS * NMODES, 256, 0, stream>>>(modes, mode_W, mode_b, proj);
    obs_mode<<<BATCH / BPB, 256, 0, stream>>>(obs, self_labels, obs_W, obs_b,
                                              mode_W, proj, out0);
    nei_gemv_mfma<<<GRID2, 256, 0, stream>>>(neis, wfrag, nei_b,
                                             counts, lists, out_n);
}